// Round 5
// baseline (489.049 us; speedup 1.0000x reference)
//
#include <hip/hip_runtime.h>
#include <hip/hip_bf16.h>

#define B_ 4
#define H_ 16
#define L_ 2048
#define D_ 1024
#define DK_ 64

typedef __attribute__((ext_vector_type(8))) __bf16 bf16x8;
typedef __attribute__((ext_vector_type(4))) __bf16 bf16x4;
typedef __attribute__((ext_vector_type(4))) float f32x4;

#define MFMA16(a, b, c) __builtin_amdgcn_mfma_f32_16x16x32_bf16(a, b, c, 0, 0, 0)

typedef const __attribute__((address_space(1))) void gv_t;
typedef __attribute__((address_space(3))) void lv_t;

// ---------------------------------------------------------------------------
// Stage NI*32 rows x 128 bytes from global (row stride gstride bf16) into a
// linear LDS tile via global_load_lds(16B). LDS dest is linear + wave-uniform
// (rule #21): lane l writes base + l*16. The global SOURCE is inverse-XOR-
// swizzled (slot s fetches data slot s^(row&7)), so LDS[row][slot] holds
// G[row][slot^(row&7)]; a swizzled read (byte ^ ((row&7)<<4)) recovers data
// and spreads 16-lane row-groups across 8 slots (~2-way conflicts = free).
// 256 threads: 8 threads/row, 32 rows per instruction.
// ---------------------------------------------------------------------------
template<int NI>
__device__ __forceinline__ void stage_swz(const __bf16* __restrict__ g,
                                          size_t gstride, __bf16* lds, int t)
{
    const int wave = t >> 6;
#pragma unroll
    for (int i = 0; i < NI; ++i) {
        const int row = i * 32 + (t >> 3);
        const int s   = (t & 7) ^ (row & 7);
        __builtin_amdgcn_global_load_lds(
            (gv_t*)(g + (size_t)row * gstride + s * 8),
            (lv_t*)(lds + (size_t)(i * 32 + wave * 8) * 64),
            16, 0, 0);
    }
}

// read one MFMA fragment (8 contiguous bf16 = 16B) from a [rows][64 bf16]
// swizzled LDS tile. kbyte = byte offset of the k-slice within the row.
__device__ __forceinline__ bf16x8 lds_frag(const __bf16* base, int row, int kbyte)
{
    const char* p = (const char*)base + row * 128 + (kbyte ^ ((row & 7) << 4));
    return *(const bf16x8*)p;
}

// ---------------------------------------------------------------------------
// cast fp32 -> bf16, 7 segments (query, key, value, Wq, Wk, Wv, Wo)
// ---------------------------------------------------------------------------
struct CastArgs {
    const float* s[7];
    __bf16*      d[7];
    int          n[7];
};

__global__ __launch_bounds__(256)
void cast_all(CastArgs a)
{
    const int seg = blockIdx.y;
    const int n   = a.n[seg];
    const float* __restrict__ s = a.s[seg];
    __bf16* __restrict__ d = a.d[seg];
    for (int i = (blockIdx.x * 256 + threadIdx.x) * 8; i < n; i += gridDim.x * 256 * 8) {
        float4 f0 = *reinterpret_cast<const float4*>(&s[i]);
        float4 f1 = *reinterpret_cast<const float4*>(&s[i + 4]);
        bf16x8 v;
        v[0] = (__bf16)f0.x; v[1] = (__bf16)f0.y; v[2] = (__bf16)f0.z; v[3] = (__bf16)f0.w;
        v[4] = (__bf16)f1.x; v[5] = (__bf16)f1.y; v[6] = (__bf16)f1.z; v[7] = (__bf16)f1.w;
        *reinterpret_cast<bf16x8*>(&d[i]) = v;
    }
}

// ---------------------------------------------------------------------------
// bf16 GEMM: C = A * W^T + bias.  A:[M,K] bf16, W:[N,K] bf16 (both row-major,
// K contiguous).  128x128 tile, BK=64, 256 threads = 4 waves (2x2), each wave
// 64x64 via 4x4 frags of mfma_f32_16x16x32_bf16.
// 1-D grid of 512 blocks, XCD-swizzled (T1): fid' = (fid%8)*64 + fid/8 gives
// each XCD 8 contiguous m-panels x all n-blocks -> A panels (2 MB) + the whole
// weight matrix (2 MB) stay L2-resident per XCD (A read ~once device-wide).
// MODE 0: head-split bf16 out [B,H,L,DK]
// MODE 1: V-transposed bf16 out [B,H,DK,L]
// MODE 2: flat fp32 out [M,N]
// ---------------------------------------------------------------------------
template<int MODE>
__global__ __launch_bounds__(256)
void gemm_bf16(const __bf16* __restrict__ A, const __bf16* __restrict__ W,
               const float* __restrict__ bias, void* __restrict__ Cout,
               int M, int N, int K)
{
    constexpr int BM = 128, BN = 128, BK = 64;
    __shared__ __bf16 As[BM * BK];
    __shared__ __bf16 Bs[BN * BK];

    const int t = threadIdx.x;
    const int wave = t >> 6, lane = t & 63;
    const int g4 = lane >> 4, l16 = lane & 15;
    const int wr = wave >> 1, wc = wave & 1;
    // XCD swizzle: 512 blocks, 8 XCDs, bijective (512 % 8 == 0)
    const int fid  = blockIdx.x;
    const int fid2 = (fid & 7) * 64 + (fid >> 3);
    const int m0 = (fid2 >> 3) * BM;
    const int n0 = (fid2 & 7) * BN;

    f32x4 acc[4][4];
#pragma unroll
    for (int m = 0; m < 4; ++m)
#pragma unroll
        for (int n = 0; n < 4; ++n) acc[m][n] = {0.f, 0.f, 0.f, 0.f};

    for (int kt = 0; kt < K; kt += BK) {
        __syncthreads();
        stage_swz<4>(A + (size_t)m0 * K + kt, (size_t)K, As, t);
        stage_swz<4>(W + (size_t)n0 * K + kt, (size_t)K, Bs, t);
        __syncthreads();   // drains vmcnt -> staged data visible
#pragma unroll
        for (int kk = 0; kk < 2; ++kk) {
            bf16x8 af[4], bfr[4];
#pragma unroll
            for (int m = 0; m < 4; ++m)
                af[m] = lds_frag(As, wr * 64 + m * 16 + l16, kk * 64 + g4 * 16);
#pragma unroll
            for (int n = 0; n < 4; ++n)
                bfr[n] = lds_frag(Bs, wc * 64 + n * 16 + l16, kk * 64 + g4 * 16);
#pragma unroll
            for (int m = 0; m < 4; ++m)
#pragma unroll
                for (int n = 0; n < 4; ++n)
                    acc[m][n] = MFMA16(af[m], bfr[n], acc[m][n]);
        }
    }

    float bv[4];
#pragma unroll
    for (int n = 0; n < 4; ++n) bv[n] = bias[n0 + wc * 64 + n * 16 + l16];

#pragma unroll
    for (int m = 0; m < 4; ++m) {
#pragma unroll
        for (int n = 0; n < 4; ++n) {
            const int gc = n0 + wc * 64 + n * 16 + l16;
            const int gr0 = m0 + wr * 64 + m * 16 + g4 * 4;
            if (MODE == 0) {           // head-split bf16: [B,H,L,DK]
                const int hh = gc >> 6, dk = gc & (DK_ - 1);
#pragma unroll
                for (int r = 0; r < 4; ++r) {
                    const int gr = gr0 + r;
                    const int bb = gr >> 11, l = gr & (L_ - 1);
                    ((__bf16*)Cout)[(((size_t)(bb * H_ + hh)) * L_ + l) * DK_ + dk] =
                        (__bf16)(acc[m][n][r] + bv[n]);
                }
            } else if (MODE == 1) {    // V^T bf16: [B,H,DK,L] (pack 4 l's = 8B)
                const int hh = gc >> 6, dk = gc & (DK_ - 1);
                const int bb = gr0 >> 11, l0 = gr0 & (L_ - 1);
                bf16x4 v;
#pragma unroll
                for (int r = 0; r < 4; ++r) v[r] = (__bf16)(acc[m][n][r] + bv[n]);
                *reinterpret_cast<bf16x4*>(
                    &((__bf16*)Cout)[(((size_t)(bb * H_ + hh)) * DK_ + dk) * L_ + l0]) = v;
            } else {                   // flat fp32
#pragma unroll
                for (int r = 0; r < 4; ++r)
                    ((float*)Cout)[(size_t)(gr0 + r) * N + gc] = acc[m][n][r] + bv[n];
            }
        }
    }
}

// ---------------------------------------------------------------------------
// Causal flash attention, bf16 MFMA + fp32 online softmax (log2 domain).
// Block: 256 threads = 4 waves; 128 q-rows/block (32 per wave); KV tiles of 64.
// Q hoisted to registers. K tile [64 keys][64 dk] and V^T tile [64 dk][64 keys]
// staged via swizzled global_load_lds. P round-trips through per-wave swizzled
// LDS (bf16) to become the PV A-operand.
// 1-D grid of 1024 blocks, XCD-swizzled: each XCD owns 8 (h,b) pairs x all 16
// q-blocks -> each head's 512 KB K/V is fetched by ONE XCD (L2-resident) and
// per-XCD causal work is exactly balanced.
// ---------------------------------------------------------------------------
#define SCALE2 0.18033688011112042f   // (1/sqrt(DK)) * log2(e): softmax in 2^x domain

__global__ __launch_bounds__(256)
void attn_mfma(const __bf16* __restrict__ Qh, const __bf16* __restrict__ Kh,
               const __bf16* __restrict__ Vt, __bf16* __restrict__ Xb)
{
    __shared__ __bf16 Ks[64 * 64];
    __shared__ __bf16 Vs[64 * 64];
    __shared__ __bf16 Ps[128 * 64];   // 4 waves x 32 rows x 64 keys

    const int t = threadIdx.x;
    const int wave = t >> 6, lane = t & 63;
    const int g4 = lane >> 4, l16 = lane & 15;
    // XCD swizzle: 1024 blocks, bijective (1024 % 8 == 0)
    const int fid  = blockIdx.x;
    const int fid2 = (fid & 7) * 128 + (fid >> 3);
    const int qblk = 15 - (fid2 & 15);      // long q-blocks first within chunk
    const int hb_id = fid2 >> 4;            // 0..63
    const int h = hb_id & 15, b = hb_id >> 4;
    const int qb = qblk * 128;
    const size_t hb = (size_t)(b * H_ + h) * L_ * DK_;
    const __bf16* Qp = Qh + hb;
    const __bf16* Kp = Kh + hb;
    const __bf16* Vp = Vt + hb;       // per-head layout [DK][L]
    const int qrow0 = qb + wave * 32;

    // hoist Q: q[m][kk], row = qrow0 + m*16 + l16, k = kk*32 + g4*8
    bf16x8 qf[2][2];
#pragma unroll
    for (int m = 0; m < 2; ++m)
#pragma unroll
        for (int kk = 0; kk < 2; ++kk)
            qf[m][kk] = *reinterpret_cast<const bf16x8*>(
                &Qp[(size_t)(qrow0 + m * 16 + l16) * DK_ + kk * 32 + g4 * 8]);

    f32x4 O[2][4];
    float m_run[2][4], l_run[2][4];
#pragma unroll
    for (int m = 0; m < 2; ++m)
#pragma unroll
        for (int r = 0; r < 4; ++r) { m_run[m][r] = -1e30f; l_run[m][r] = 0.f; }
#pragma unroll
    for (int m = 0; m < 2; ++m)
#pragma unroll
        for (int n = 0; n < 4; ++n) O[m][n] = {0.f, 0.f, 0.f, 0.f};

    const int ntile = qb / 64 + 2;
    for (int it = 0; it < ntile; ++it) {
        const int kv0 = it * 64;
        __syncthreads();
        stage_swz<2>(Kp + (size_t)kv0 * DK_, DK_, Ks, t);
        stage_swz<2>(Vp + kv0, L_, Vs, t);
        __syncthreads();   // drains vmcnt -> K/V visible
        if (kv0 > qrow0 + 31) continue;   // fully masked for this wave

        // ---- S = Q K^T (16 MFMA) ----
        f32x4 s[2][4];
#pragma unroll
        for (int m = 0; m < 2; ++m)
#pragma unroll
            for (int n = 0; n < 4; ++n) s[m][n] = {0.f, 0.f, 0.f, 0.f};
        __builtin_amdgcn_s_setprio(1);
#pragma unroll
        for (int kk = 0; kk < 2; ++kk) {
            bf16x8 kf[4];
#pragma unroll
            for (int n = 0; n < 4; ++n)
                kf[n] = lds_frag(Ks, n * 16 + l16, kk * 64 + g4 * 16);
#pragma unroll
            for (int m = 0; m < 2; ++m)
#pragma unroll
                for (int n = 0; n < 4; ++n)
                    s[m][n] = MFMA16(qf[m][kk], kf[n], s[m][n]);
        }
        __builtin_amdgcn_s_setprio(0);

        // ---- scale (log2 domain) + causal mask ----
        // mask needed iff any key in tile exceeds any row of this wave:
        // max key = kv0+63, min row = qrow0.  (round-2/3 compared against
        // qrow0+31 = last row -> leaked future keys for rows < last. FIXED.)
        if (kv0 + 63 > qrow0) {
#pragma unroll
            for (int m = 0; m < 2; ++m)
#pragma unroll
                for (int n = 0; n < 4; ++n)
#pragma unroll
                    for (int r = 0; r < 4; ++r) {
                        const int qg = qrow0 + m * 16 + g4 * 4 + r;
                        const int kg = kv0 + n * 16 + l16;
                        s[m][n][r] = (kg <= qg) ? s[m][n][r] * SCALE2 : -1e30f;
                    }
        } else {
#pragma unroll
            for (int m = 0; m < 2; ++m)
#pragma unroll
                for (int n = 0; n < 4; ++n)
#pragma unroll
                    for (int r = 0; r < 4; ++r)
                        s[m][n][r] *= SCALE2;
        }

        // ---- online softmax: exp2-based, row stats across 16-lane col group ----
        float al[2][4];
#pragma unroll
        for (int m = 0; m < 2; ++m)
#pragma unroll
            for (int r = 0; r < 4; ++r) {
                float mx = fmaxf(fmaxf(s[m][0][r], s[m][1][r]),
                                 fmaxf(s[m][2][r], s[m][3][r]));
                mx = fmaxf(mx, __shfl_xor(mx, 1));
                mx = fmaxf(mx, __shfl_xor(mx, 2));
                mx = fmaxf(mx, __shfl_xor(mx, 4));
                mx = fmaxf(mx, __shfl_xor(mx, 8));
                const float mn = fmaxf(m_run[m][r], mx);
                al[m][r] = exp2f(m_run[m][r] - mn);
                m_run[m][r] = mn;
                float lb = 0.f;
#pragma unroll
                for (int n = 0; n < 4; ++n) {
                    const float p = exp2f(s[m][n][r] - mn);
                    s[m][n][r] = p;
                    lb += p;
                }
                lb += __shfl_xor(lb, 1);
                lb += __shfl_xor(lb, 2);
                lb += __shfl_xor(lb, 4);
                lb += __shfl_xor(lb, 8);
                l_run[m][r] = al[m][r] * l_run[m][r] + lb;
            }

        // ---- P -> per-wave LDS (bf16, swizzled), rescale O ----
        char* Pw = (char*)Ps + wave * 32 * 128;
#pragma unroll
        for (int m = 0; m < 2; ++m)
#pragma unroll
            for (int r = 0; r < 4; ++r) {
                const int R = m * 16 + g4 * 4 + r;
#pragma unroll
                for (int n = 0; n < 4; ++n)
                    *(__bf16*)(Pw + R * 128 + ((n * 32 + l16 * 2) ^ ((R & 7) << 4))) =
                        (__bf16)s[m][n][r];
#pragma unroll
                for (int n = 0; n < 4; ++n) O[m][n][r] *= al[m][r];
            }

        // ---- O += P V (16 MFMA) ----
        const __bf16* Pr = Ps + wave * 32 * 64;
        __builtin_amdgcn_s_setprio(1);
#pragma unroll
        for (int kk = 0; kk < 2; ++kk) {
            bf16x8 pa[2], vf[4];
#pragma unroll
            for (int m = 0; m < 2; ++m)
                pa[m] = lds_frag(Pr, m * 16 + l16, kk * 64 + g4 * 16);
#pragma unroll
            for (int n = 0; n < 4; ++n)
                vf[n] = lds_frag(Vs, n * 16 + l16, kk * 64 + g4 * 16);
#pragma unroll
            for (int m = 0; m < 2; ++m)
#pragma unroll
                for (int n = 0; n < 4; ++n)
                    O[m][n] = MFMA16(pa[m], vf[n], O[m][n]);
        }
        __builtin_amdgcn_s_setprio(0);
    }

    // ---- epilogue: normalize, write X bf16 [B, L, D] head-merged ----
#pragma unroll
    for (int m = 0; m < 2; ++m)
#pragma unroll
        for (int r = 0; r < 4; ++r) {
            const float inv = 1.0f / l_run[m][r];
            const int qrow = qrow0 + m * 16 + g4 * 4 + r;
#pragma unroll
            for (int n = 0; n < 4; ++n)
                Xb[((size_t)b * L_ + qrow) * D_ + h * DK_ + n * 16 + l16] =
                    (__bf16)(O[m][n][r] * inv);
        }
}

// ---------------------------------------------------------------------------
extern "C" void kernel_launch(void* const* d_in, const int* in_sizes, int n_in,
                              void* d_out, int out_size, void* d_ws, size_t ws_size,
                              hipStream_t stream)
{
    (void)in_sizes; (void)n_in; (void)out_size; (void)ws_size;
    const float* query = (const float*)d_in[0];
    const float* key   = (const float*)d_in[1];
    const float* value = (const float*)d_in[2];
    // d_in[3] = mask: exactly the causal tril -> handled analytically
    const float* Wq = (const float*)d_in[4];
    const float* bq = (const float*)d_in[5];
    const float* Wk = (const float*)d_in[6];
    const float* bk = (const float*)d_in[7];
    const float* Wv = (const float*)d_in[8];
    const float* bv = (const float*)d_in[9];
    const float* Wo = (const float*)d_in[10];
    const float* bo = (const float*)d_in[11];

    const size_t SZ = (size_t)B_ * L_ * D_;       // 8,388,608
    const size_t WSZ = (size_t)D_ * D_;           // 1,048,576
    __bf16* wsb = (__bf16*)d_ws;                  // total 62.9M bf16 = 125.8 MB
    __bf16* qb_ = wsb;
    __bf16* kb_ = wsb + SZ;
    __bf16* vb_ = wsb + 2 * SZ;
    __bf16* Qh  = wsb + 3 * SZ;
    __bf16* Kh  = wsb + 4 * SZ;
    __bf16* Vt  = wsb + 5 * SZ;
    __bf16* Xb  = wsb + 6 * SZ;
    __bf16* Wqb = wsb + 7 * SZ;
    __bf16* Wkb = Wqb + WSZ;
    __bf16* Wvb = Wkb + WSZ;
    __bf16* Wob = Wvb + WSZ;

    CastArgs ca;
    ca.s[0] = query; ca.s[1] = key; ca.s[2] = value;
    ca.s[3] = Wq; ca.s[4] = Wk; ca.s[5] = Wv; ca.s[6] = Wo;
    ca.d[0] = qb_; ca.d[1] = kb_; ca.d[2] = vb_;
    ca.d[3] = Wqb; ca.d[4] = Wkb; ca.d[5] = Wvb; ca.d[6] = Wob;
    ca.n[0] = ca.n[1] = ca.n[2] = (int)SZ;
    ca.n[3] = ca.n[4] = ca.n[5] = ca.n[6] = (int)WSZ;
    cast_all<<<dim3(1024, 7), 256, 0, stream>>>(ca);

    const int M = B_ * L_;
    const int ngemm = (M / 128) * (D_ / 128);     // 512 blocks, 1-D swizzled grid
    gemm_bf16<0><<<ngemm, 256, 0, stream>>>(qb_, Wqb, bq, Qh, M, D_, D_);
    gemm_bf16<0><<<ngemm, 256, 0, stream>>>(kb_, Wkb, bk, Kh, M, D_, D_);
    gemm_bf16<1><<<ngemm, 256, 0, stream>>>(vb_, Wvb, bv, Vt, M, D_, D_);
    attn_mfma<<<(L_ / 128) * H_ * B_, 256, 0, stream>>>(Qh, Kh, Vt, Xb);
    gemm_bf16<2><<<ngemm, 256, 0, stream>>>(Xb, Wob, bo, d_out, M, D_, D_);
}

// Round 6
// 401.174 us; speedup vs baseline: 1.2190x; 1.2190x over previous
//
#include <hip/hip_runtime.h>
#include <hip/hip_bf16.h>

#define B_ 4
#define H_ 16
#define L_ 2048
#define D_ 1024
#define DK_ 64

typedef __attribute__((ext_vector_type(8))) __bf16 bf16x8;
typedef __attribute__((ext_vector_type(4))) __bf16 bf16x4;
typedef __attribute__((ext_vector_type(4))) float f32x4;

#define MFMA16(a, b, c) __builtin_amdgcn_mfma_f32_16x16x32_bf16(a, b, c, 0, 0, 0)

typedef const __attribute__((address_space(1))) void gv_t;
typedef __attribute__((address_space(3))) void lv_t;

// ---------------------------------------------------------------------------
// Stage NI*32 rows x 128 bytes from global (row stride gstride bf16) into a
// linear LDS tile via global_load_lds(16B). LDS dest is linear + wave-uniform
// (rule #21); global SOURCE is inverse-XOR-swizzled (slot s fetches slot
// s^(row&7)), so a swizzled read (byte ^ ((row&7)<<4)) recovers data with
// ~2-way (free) bank aliasing. 256 threads: 8 threads/row, 32 rows/inst.
// ---------------------------------------------------------------------------
template<int NI>
__device__ __forceinline__ void stage_swz(const __bf16* __restrict__ g,
                                          size_t gstride, __bf16* lds, int t)
{
    const int wave = t >> 6;
#pragma unroll
    for (int i = 0; i < NI; ++i) {
        const int row = i * 32 + (t >> 3);
        const int s   = (t & 7) ^ (row & 7);
        __builtin_amdgcn_global_load_lds(
            (gv_t*)(g + (size_t)row * gstride + s * 8),
            (lv_t*)(lds + (size_t)(i * 32 + wave * 8) * 64),
            16, 0, 0);
    }
}

// read one MFMA fragment (8 contiguous bf16 = 16B) from a [rows][64 bf16]
// swizzled LDS tile. kbyte = byte offset of the k-slice within the row.
__device__ __forceinline__ bf16x8 lds_frag(const __bf16* base, int row, int kbyte)
{
    const char* p = (const char*)base + row * 128 + (kbyte ^ ((row & 7) << 4));
    return *(const bf16x8*)p;
}

// ---------------------------------------------------------------------------
// cast fp32 -> bf16, 7 segments (query, key, value, Wq, Wk, Wv, Wo)
// ---------------------------------------------------------------------------
struct CastArgs {
    const float* s[7];
    __bf16*      d[7];
    int          n[7];
};

__global__ __launch_bounds__(256)
void cast_all(CastArgs a)
{
    const int seg = blockIdx.y;
    const int n   = a.n[seg];
    const float* __restrict__ s = a.s[seg];
    __bf16* __restrict__ d = a.d[seg];
    for (int i = (blockIdx.x * 256 + threadIdx.x) * 8; i < n; i += gridDim.x * 256 * 8) {
        float4 f0 = *reinterpret_cast<const float4*>(&s[i]);
        float4 f1 = *reinterpret_cast<const float4*>(&s[i + 4]);
        bf16x8 v;
        v[0] = (__bf16)f0.x; v[1] = (__bf16)f0.y; v[2] = (__bf16)f0.z; v[3] = (__bf16)f0.w;
        v[4] = (__bf16)f1.x; v[5] = (__bf16)f1.y; v[6] = (__bf16)f1.z; v[7] = (__bf16)f1.w;
        *reinterpret_cast<bf16x8*>(&d[i]) = v;
    }
}

// ---------------------------------------------------------------------------
// bf16 GEMM: C = A * W^T + bias, 2-phase double-buffered staging (T3-min):
// issue STAGE(t+1) before compute(t); ONE vmcnt-drain barrier per K-step.
// 128x128 tile, BK=64, 256 threads = 4 waves (2x2), 4x4 frags each.
// LDS 64 KB -> 2 blocks/CU (= grid share).
// XCD swizzle (T1): fid' = (fid%8)*64 + fid/8 -> per-XCD m-panels + W L2-hot.
// MODE 0: head-split bf16 out [B,H,L,DK]
// MODE 1: V-transposed bf16 out [B,H,DK,L]
// MODE 2: flat fp32 out [M,N]
// ---------------------------------------------------------------------------
template<int MODE>
__global__ __launch_bounds__(256)
void gemm_bf16(const __bf16* __restrict__ A, const __bf16* __restrict__ W,
               const float* __restrict__ bias, void* __restrict__ Cout,
               int M, int N, int K)
{
    constexpr int BM = 128, BN = 128, BK = 64;
    __shared__ __bf16 As[2][BM * BK];
    __shared__ __bf16 Bs[2][BN * BK];

    const int t = threadIdx.x;
    const int wave = t >> 6, lane = t & 63;
    const int g4 = lane >> 4, l16 = lane & 15;
    const int wr = wave >> 1, wc = wave & 1;
    // XCD swizzle: 512 blocks, 8 XCDs, bijective (512 % 8 == 0)
    const int fid  = blockIdx.x;
    const int fid2 = (fid & 7) * 64 + (fid >> 3);
    const int m0 = (fid2 >> 3) * BM;
    const int n0 = (fid2 & 7) * BN;

    f32x4 acc[4][4];
#pragma unroll
    for (int m = 0; m < 4; ++m)
#pragma unroll
        for (int n = 0; n < 4; ++n) acc[m][n] = {0.f, 0.f, 0.f, 0.f};

    const int nt = K / BK;          // 16
    stage_swz<4>(A + (size_t)m0 * K, (size_t)K, As[0], t);
    stage_swz<4>(W + (size_t)n0 * K, (size_t)K, Bs[0], t);
    __syncthreads();                // tile 0 resident

    int cur = 0;
    for (int ti = 0; ti < nt; ++ti) {
        if (ti + 1 < nt) {          // prefetch next K-step into alt buffer
            stage_swz<4>(A + (size_t)m0 * K + (ti + 1) * BK, (size_t)K, As[cur ^ 1], t);
            stage_swz<4>(W + (size_t)n0 * K + (ti + 1) * BK, (size_t)K, Bs[cur ^ 1], t);
        }
#pragma unroll
        for (int kk = 0; kk < 2; ++kk) {
            bf16x8 af[4], bfr[4];
#pragma unroll
            for (int m = 0; m < 4; ++m)
                af[m] = lds_frag(As[cur], wr * 64 + m * 16 + l16, kk * 64 + g4 * 16);
#pragma unroll
            for (int n = 0; n < 4; ++n)
                bfr[n] = lds_frag(Bs[cur], wc * 64 + n * 16 + l16, kk * 64 + g4 * 16);
#pragma unroll
            for (int m = 0; m < 4; ++m)
#pragma unroll
                for (int n = 0; n < 4; ++n)
                    acc[m][n] = MFMA16(af[m], bfr[n], acc[m][n]);
        }
        __syncthreads();            // drains vmcnt (prefetch) + lgkm; 1/iter
        cur ^= 1;
    }

    float bv[4];
#pragma unroll
    for (int n = 0; n < 4; ++n) bv[n] = bias[n0 + wc * 64 + n * 16 + l16];

#pragma unroll
    for (int m = 0; m < 4; ++m) {
#pragma unroll
        for (int n = 0; n < 4; ++n) {
            const int gc = n0 + wc * 64 + n * 16 + l16;
            const int gr0 = m0 + wr * 64 + m * 16 + g4 * 4;
            if (MODE == 0) {           // head-split bf16: [B,H,L,DK]
                const int hh = gc >> 6, dk = gc & (DK_ - 1);
#pragma unroll
                for (int r = 0; r < 4; ++r) {
                    const int gr = gr0 + r;
                    const int bb = gr >> 11, l = gr & (L_ - 1);
                    ((__bf16*)Cout)[(((size_t)(bb * H_ + hh)) * L_ + l) * DK_ + dk] =
                        (__bf16)(acc[m][n][r] + bv[n]);
                }
            } else if (MODE == 1) {    // V^T bf16: [B,H,DK,L] (pack 4 l's = 8B)
                const int hh = gc >> 6, dk = gc & (DK_ - 1);
                const int bb = gr0 >> 11, l0 = gr0 & (L_ - 1);
                bf16x4 v;
#pragma unroll
                for (int r = 0; r < 4; ++r) v[r] = (__bf16)(acc[m][n][r] + bv[n]);
                *reinterpret_cast<bf16x4*>(
                    &((__bf16*)Cout)[(((size_t)(bb * H_ + hh)) * DK_ + dk) * L_ + l0]) = v;
            } else {                   // flat fp32
#pragma unroll
                for (int r = 0; r < 4; ++r)
                    ((float*)Cout)[(size_t)(gr0 + r) * N + gc] = acc[m][n][r] + bv[n];
            }
        }
    }
}

// ---------------------------------------------------------------------------
// Causal flash attention, bf16 MFMA + fp32 online softmax (log2 domain).
// Round-6 restructure (fixes 14% occupancy / CU load-imbalance):
//  - QBLK=64 rows/block, 4 waves x 16 rows; KVBLK=64. Grid 2048 (8/CU).
//  - Longest-strip-first per XCD; 8 (h,b) pairs per XCD (K+V = 4MB = L2).
//  - 2-phase double-buffered K/V staging: STAGE(t+1) issued before
//    compute(t); ONE vmcnt-drain barrier per tile (was 2 + no prefetch).
//  - Diagonal tile (it == strip) is the only masked one; no skipped tiles.
// LDS 40 KB -> 4 blocks/CU.
// ---------------------------------------------------------------------------
#define SCALE2 0.18033688011112042f   // (1/sqrt(DK)) * log2(e)

__global__ __launch_bounds__(256)
void attn_mfma(const __bf16* __restrict__ Qh, const __bf16* __restrict__ Kh,
               const __bf16* __restrict__ Vt, __bf16* __restrict__ Xb)
{
    __shared__ __bf16 Ks[2][64 * 64];
    __shared__ __bf16 Vs[2][64 * 64];
    __shared__ __bf16 Ps[64 * 64];    // 4 waves x 16 rows x 64 keys

    const int t = threadIdx.x;
    const int wave = t >> 6, lane = t & 63;
    const int g4 = lane >> 4, l16 = lane & 15;
    // fid -> (xcd, strip, hb): 2048 blocks, bijective. Within an XCD the
    // dispatch order is strip 31 (longest) first across its 8 hb pairs.
    const int fid   = blockIdx.x;
    const int xcd   = fid & 7;
    const int idx   = fid >> 3;          // 0..255 within XCD
    const int strip = 31 - (idx >> 3);   // 32 q-strips of 64 rows, long first
    const int hb_id = xcd * 8 + (idx & 7);
    const int h = hb_id & 15, b = hb_id >> 4;
    const int qb = strip * 64;
    const size_t hb = (size_t)(b * H_ + h) * L_ * DK_;
    const __bf16* Qp = Qh + hb;
    const __bf16* Kp = Kh + hb;
    const __bf16* Vp = Vt + hb;          // per-head layout [DK][L]
    const int qrow0 = qb + wave * 16;

    // hoist Q: row = qrow0 + l16, k = kk*32 + g4*8
    bf16x8 qf[2];
#pragma unroll
    for (int kk = 0; kk < 2; ++kk)
        qf[kk] = *reinterpret_cast<const bf16x8*>(
            &Qp[(size_t)(qrow0 + l16) * DK_ + kk * 32 + g4 * 8]);

    f32x4 O[4];
    float m_run[4], l_run[4];
#pragma unroll
    for (int r = 0; r < 4; ++r) { m_run[r] = -1e30f; l_run[r] = 0.f; }
#pragma unroll
    for (int n = 0; n < 4; ++n) O[n] = {0.f, 0.f, 0.f, 0.f};

    const int ntile = strip + 1;
    // prologue: stage tile 0
    stage_swz<2>(Kp, DK_, Ks[0], t);
    stage_swz<2>(Vp, L_, Vs[0], t);
    __syncthreads();

    int cur = 0;
    for (int it = 0; it < ntile; ++it) {
        if (it + 1 < ntile) {            // prefetch next K/V tile
            stage_swz<2>(Kp + (size_t)(it + 1) * 64 * DK_, DK_, Ks[cur ^ 1], t);
            stage_swz<2>(Vp + (it + 1) * 64, L_, Vs[cur ^ 1], t);
        }
        const int kv0 = it * 64;

        // ---- S = Q K^T (8 MFMA) ----
        f32x4 s[4];
#pragma unroll
        for (int n = 0; n < 4; ++n) s[n] = {0.f, 0.f, 0.f, 0.f};
        __builtin_amdgcn_s_setprio(1);
#pragma unroll
        for (int kk = 0; kk < 2; ++kk) {
            bf16x8 kf[4];
#pragma unroll
            for (int n = 0; n < 4; ++n)
                kf[n] = lds_frag(Ks[cur], n * 16 + l16, kk * 64 + g4 * 16);
#pragma unroll
            for (int n = 0; n < 4; ++n)
                s[n] = MFMA16(qf[kk], kf[n], s[n]);
        }
        __builtin_amdgcn_s_setprio(0);

        // ---- scale (log2 domain) + causal mask (diagonal tile only) ----
        if (it == strip) {
#pragma unroll
            for (int n = 0; n < 4; ++n)
#pragma unroll
                for (int r = 0; r < 4; ++r) {
                    const int qg = qrow0 + g4 * 4 + r;
                    const int kg = kv0 + n * 16 + l16;
                    s[n][r] = (kg <= qg) ? s[n][r] * SCALE2 : -1e30f;
                }
        } else {
#pragma unroll
            for (int n = 0; n < 4; ++n)
#pragma unroll
                for (int r = 0; r < 4; ++r)
                    s[n][r] *= SCALE2;
        }

        // ---- online softmax: exp2, row stats across 16-lane col group ----
        float al[4];
#pragma unroll
        for (int r = 0; r < 4; ++r) {
            float mx = fmaxf(fmaxf(s[0][r], s[1][r]), fmaxf(s[2][r], s[3][r]));
            mx = fmaxf(mx, __shfl_xor(mx, 1));
            mx = fmaxf(mx, __shfl_xor(mx, 2));
            mx = fmaxf(mx, __shfl_xor(mx, 4));
            mx = fmaxf(mx, __shfl_xor(mx, 8));
            const float mn = fmaxf(m_run[r], mx);
            al[r] = exp2f(m_run[r] - mn);
            m_run[r] = mn;
            float lb = 0.f;
#pragma unroll
            for (int n = 0; n < 4; ++n) {
                const float p = exp2f(s[n][r] - mn);
                s[n][r] = p;
                lb += p;
            }
            lb += __shfl_xor(lb, 1);
            lb += __shfl_xor(lb, 2);
            lb += __shfl_xor(lb, 4);
            lb += __shfl_xor(lb, 8);
            l_run[r] = al[r] * l_run[r] + lb;
        }

        // ---- P -> per-wave LDS (bf16, swizzled), rescale O ----
        char* Pw = (char*)Ps + wave * 16 * 128;
#pragma unroll
        for (int r = 0; r < 4; ++r) {
            const int R = g4 * 4 + r;
#pragma unroll
            for (int n = 0; n < 4; ++n)
                *(__bf16*)(Pw + R * 128 + ((n * 32 + l16 * 2) ^ ((R & 7) << 4))) =
                    (__bf16)s[n][r];
#pragma unroll
            for (int n = 0; n < 4; ++n) O[n][r] *= al[r];
        }

        // ---- O += P V (8 MFMA) ----
        const __bf16* Pr = Ps + wave * 16 * 64;
        __builtin_amdgcn_s_setprio(1);
#pragma unroll
        for (int kk = 0; kk < 2; ++kk) {
            bf16x8 pa = lds_frag(Pr, l16, kk * 64 + g4 * 16);
            bf16x8 vf[4];
#pragma unroll
            for (int n = 0; n < 4; ++n)
                vf[n] = lds_frag(Vs[cur], n * 16 + l16, kk * 64 + g4 * 16);
#pragma unroll
            for (int n = 0; n < 4; ++n)
                O[n] = MFMA16(pa, vf[n], O[n]);
        }
        __builtin_amdgcn_s_setprio(0);

        __syncthreads();   // drains vmcnt (prefetch) + lgkm; 1 barrier/tile
        cur ^= 1;
    }

    // ---- epilogue: normalize, write X bf16 [B, L, D] head-merged ----
#pragma unroll
    for (int r = 0; r < 4; ++r) {
        const float inv = 1.0f / l_run[r];
        const int qrow = qrow0 + g4 * 4 + r;
#pragma unroll
        for (int n = 0; n < 4; ++n)
            Xb[((size_t)b * L_ + qrow) * D_ + h * DK_ + n * 16 + l16] =
                (__bf16)(O[n][r] * inv);
    }
}

// ---------------------------------------------------------------------------
extern "C" void kernel_launch(void* const* d_in, const int* in_sizes, int n_in,
                              void* d_out, int out_size, void* d_ws, size_t ws_size,
                              hipStream_t stream)
{
    (void)in_sizes; (void)n_in; (void)out_size; (void)ws_size;
    const float* query = (const float*)d_in[0];
    const float* key   = (const float*)d_in[1];
    const float* value = (const float*)d_in[2];
    // d_in[3] = mask: exactly the causal tril -> handled analytically
    const float* Wq = (const float*)d_in[4];
    const float* bq = (const float*)d_in[5];
    const float* Wk = (const float*)d_in[6];
    const float* bk = (const float*)d_in[7];
    const float* Wv = (const float*)d_in[8];
    const float* bv = (const float*)d_in[9];
    const float* Wo = (const float*)d_in[10];
    const float* bo = (const float*)d_in[11];

    const size_t SZ = (size_t)B_ * L_ * D_;       // 8,388,608
    const size_t WSZ = (size_t)D_ * D_;           // 1,048,576
    __bf16* wsb = (__bf16*)d_ws;                  // total 62.9M bf16 = 125.8 MB
    __bf16* qb_ = wsb;
    __bf16* kb_ = wsb + SZ;
    __bf16* vb_ = wsb + 2 * SZ;
    __bf16* Qh  = wsb + 3 * SZ;
    __bf16* Kh  = wsb + 4 * SZ;
    __bf16* Vt  = wsb + 5 * SZ;
    __bf16* Xb  = wsb + 6 * SZ;
    __bf16* Wqb = wsb + 7 * SZ;
    __bf16* Wkb = Wqb + WSZ;
    __bf16* Wvb = Wkb + WSZ;
    __bf16* Wob = Wvb + WSZ;

    CastArgs ca;
    ca.s[0] = query; ca.s[1] = key; ca.s[2] = value;
    ca.s[3] = Wq; ca.s[4] = Wk; ca.s[5] = Wv; ca.s[6] = Wo;
    ca.d[0] = qb_; ca.d[1] = kb_; ca.d[2] = vb_;
    ca.d[3] = Wqb; ca.d[4] = Wkb; ca.d[5] = Wvb; ca.d[6] = Wob;
    ca.n[0] = ca.n[1] = ca.n[2] = (int)SZ;
    ca.n[3] = ca.n[4] = ca.n[5] = ca.n[6] = (int)WSZ;
    cast_all<<<dim3(1024, 7), 256, 0, stream>>>(ca);

    const int M = B_ * L_;
    const int ngemm = (M / 128) * (D_ / 128);     // 512 blocks, 1-D swizzled grid
    gemm_bf16<0><<<ngemm, 256, 0, stream>>>(qb_, Wqb, bq, Qh, M, D_, D_);
    gemm_bf16<0><<<ngemm, 256, 0, stream>>>(kb_, Wkb, bk, Kh, M, D_, D_);
    gemm_bf16<1><<<ngemm, 256, 0, stream>>>(vb_, Wvb, bv, Vt, M, D_, D_);
    attn_mfma<<<32 * H_ * B_, 256, 0, stream>>>(Qh, Kh, Vt, Xb);
    gemm_bf16<2><<<ngemm, 256, 0, stream>>>(Xb, Wob, bo, d_out, M, D_, D_);
}

// Round 7
// 349.617 us; speedup vs baseline: 1.3988x; 1.1475x over previous
//
#include <hip/hip_runtime.h>
#include <hip/hip_bf16.h>

#define B_ 4
#define H_ 16
#define L_ 2048
#define D_ 1024
#define DK_ 64

typedef __attribute__((ext_vector_type(8))) __bf16 bf16x8;
typedef __attribute__((ext_vector_type(4))) __bf16 bf16x4;
typedef __attribute__((ext_vector_type(4))) float f32x4;

#define MFMA16(a, b, c) __builtin_amdgcn_mfma_f32_16x16x32_bf16(a, b, c, 0, 0, 0)

typedef const __attribute__((address_space(1))) void gv_t;
typedef __attribute__((address_space(3))) void lv_t;

template<int NI>
__device__ __forceinline__ void stage_swz(const __bf16* __restrict__ g,
                                          size_t gstride, __bf16* lds, int t)
{
    const int wave = t >> 6;
#pragma unroll
    for (int i = 0; i < NI; ++i) {
        const int row = i * 32 + (t >> 3);
        const int s   = (t & 7) ^ (row & 7);
        __builtin_amdgcn_global_load_lds(
            (gv_t*)(g + (size_t)row * gstride + s * 8),
            (lv_t*)(lds + (size_t)(i * 32 + wave * 8) * 64),
            16, 0, 0);
    }
}

__device__ __forceinline__ bf16x8 lds_frag(const __bf16* base, int row, int kbyte)
{
    const char* p = (const char*)base + row * 128 + (kbyte ^ ((row & 7) << 4));
    return *(const bf16x8*)p;
}

struct CastArgs {
    const float* s[7];
    __bf16*      d[7];
    int          n[7];
};

__global__ __launch_bounds__(256)
void cast_all(CastArgs a)
{
    const int seg = blockIdx.y;
    const int n   = a.n[seg];
    const float* __restrict__ s = a.s[seg];
    __bf16* __restrict__ d = a.d[seg];
    for (int i = (blockIdx.x * 256 + threadIdx.x) * 8; i < n; i += gridDim.x * 256 * 8) {
        float4 f0 = *reinterpret_cast<const float4*>(&s[i]);
        float4 f1 = *reinterpret_cast<const float4*>(&s[i + 4]);
        bf16x8 v;
        v[0] = (__bf16)f0.x; v[1] = (__bf16)f0.y; v[2] = (__bf16)f0.z; v[3] = (__bf16)f0.w;
        v[4] = (__bf16)f1.x; v[5] = (__bf16)f1.y; v[6] = (__bf16)f1.z; v[7] = (__bf16)f1.w;
        *reinterpret_cast<bf16x8*>(&d[i]) = v;
    }
}

// ---------------------------------------------------------------------------
// bf16 GEMM, BM=128 BN=64 BK=64, single-buffer m97 2-barrier loop, 4 waves
// (2x2; wave tile 64x32 = 4x2 frags). LDS 24KB + launch_bounds(256,4) ->
// 4 blocks/CU resident for inter-block overlap (m114).
// MODE 2: C = A*W^T + bias, fp32 flat [M,N].
// MODE 3: fused QKV batch: grid spans N=3072; which = n0>>10 selects the
//         A segment (q/k/v bf16, contiguous at stride ASEG) and the output
//         (Q/K head-split bf16 [B,H,L,DK]; V transposed bf16 [B,H,DK,L]).
// ---------------------------------------------------------------------------
struct QKVDst {
    const float* bq; const float* bk; const float* bvv;
    __bf16* qh; __bf16* kh; __bf16* vt;
};

#define ASEG ((size_t)B_ * L_ * D_)

template<int MODE>
__global__ __launch_bounds__(256, 4)
void gemm_bf16(const __bf16* __restrict__ A, const __bf16* __restrict__ W,
               const float* __restrict__ bias, void* __restrict__ Cout,
               int M, int N, int K, QKVDst qd)
{
    constexpr int BM = 128, BN = 64, BK = 64;
    __shared__ __bf16 As[BM * BK];
    __shared__ __bf16 Bs[BN * BK];

    const int t = threadIdx.x;
    const int wave = t >> 6, lane = t & 63;
    const int g4 = lane >> 4, l16 = lane & 15;
    const int wr = wave >> 1, wc = wave & 1;
    const int fid = blockIdx.x;
    const int idx = fid >> 3;
    const int m0 = (((fid & 7) << 3) + (idx & 7)) * BM;   // 64 m-panels, 8/XCD
    const int n0 = (idx >> 3) * BN;
    const int which = (MODE == 3) ? (n0 >> 10) : 0;        // uniform per block
    if (MODE == 3) A += (size_t)which * ASEG;              // pick q/k/v input

    f32x4 acc[4][2];
#pragma unroll
    for (int m = 0; m < 4; ++m)
#pragma unroll
        for (int n = 0; n < 2; ++n) acc[m][n] = {0.f, 0.f, 0.f, 0.f};

    for (int kt = 0; kt < K; kt += BK) {
        __syncthreads();
        stage_swz<4>(A + (size_t)m0 * K + kt, (size_t)K, As, t);
        stage_swz<2>(W + (size_t)n0 * K + kt, (size_t)K, Bs, t);
        __syncthreads();   // drains vmcnt -> staged data visible
#pragma unroll
        for (int kk = 0; kk < 2; ++kk) {
            bf16x8 af[4], bfr[2];
#pragma unroll
            for (int m = 0; m < 4; ++m)
                af[m] = lds_frag(As, wr * 64 + m * 16 + l16, kk * 64 + g4 * 16);
#pragma unroll
            for (int n = 0; n < 2; ++n)
                bfr[n] = lds_frag(Bs, wc * 32 + n * 16 + l16, kk * 64 + g4 * 16);
#pragma unroll
            for (int m = 0; m < 4; ++m)
#pragma unroll
                for (int n = 0; n < 2; ++n)
                    acc[m][n] = MFMA16(af[m], bfr[n], acc[m][n]);
        }
    }

#pragma unroll
    for (int n = 0; n < 2; ++n) {
        const int gc = n0 + wc * 32 + n * 16 + l16;
        float bval;
        int dd = gc, hh = 0, dk = 0;
        if (MODE == 3) {
            dd = gc & 1023; hh = dd >> 6; dk = dd & 63;
            const float* bp = (which == 0) ? qd.bq : (which == 1) ? qd.bk : qd.bvv;
            bval = bp[dd];
        } else {
            bval = bias[gc];
        }
#pragma unroll
        for (int m = 0; m < 4; ++m) {
            const int gr0 = m0 + wr * 64 + m * 16 + g4 * 4;
            if (MODE == 3) {
                const int bb = gr0 >> 11, l0 = gr0 & (L_ - 1);
                if (which < 2) {
                    __bf16* dst = (which == 0) ? qd.qh : qd.kh;
#pragma unroll
                    for (int r = 0; r < 4; ++r)
                        dst[(((size_t)(bb * H_ + hh)) * L_ + l0 + r) * DK_ + dk] =
                            (__bf16)(acc[m][n][r] + bval);
                } else {
                    bf16x4 v;
#pragma unroll
                    for (int r = 0; r < 4; ++r) v[r] = (__bf16)(acc[m][n][r] + bval);
                    *reinterpret_cast<bf16x4*>(
                        &qd.vt[(((size_t)(bb * H_ + hh)) * DK_ + dk) * L_ + l0]) = v;
                }
            } else {
#pragma unroll
                for (int r = 0; r < 4; ++r)
                    ((float*)Cout)[(size_t)(gr0 + r) * N + gc] = acc[m][n][r] + bval;
            }
        }
    }
}

// ---------------------------------------------------------------------------
// Causal flash attention: swapped QK^T (lane-local softmax) + defer-max.
// st[n][r] = S[q = l16][key = n*16+g4*4+r]; row reduce = 15 in-reg ops +
// 2 shfl (was 32 shfl). P written as packed bf16x4. O rescale skipped when
// tile max growth <= THR (wave-uniform). K/V dbuf prefetch, 1 barrier/tile.
// ---------------------------------------------------------------------------
#define SCALE2 0.18033688011112042f   // (1/sqrt(DK)) * log2(e)
#define THR    6.0f

__global__ __launch_bounds__(256, 4)
void attn_mfma(const __bf16* __restrict__ Qh, const __bf16* __restrict__ Kh,
               const __bf16* __restrict__ Vt, __bf16* __restrict__ Xb)
{
    __shared__ __bf16 Ks[2][64 * 64];
    __shared__ __bf16 Vs[2][64 * 64];
    __shared__ __bf16 Ps[64 * 64];

    const int t = threadIdx.x;
    const int wave = t >> 6, lane = t & 63;
    const int g4 = lane >> 4, l16 = lane & 15;
    const int fid   = blockIdx.x;
    const int xcd   = fid & 7;
    const int idx   = fid >> 3;
    const int strip = 31 - (idx >> 3);
    const int hb_id = xcd * 8 + (idx & 7);
    const int h = hb_id & 15, b = hb_id >> 4;
    const int qb = strip * 64;
    const size_t hb = (size_t)(b * H_ + h) * L_ * DK_;
    const __bf16* Qp = Qh + hb;
    const __bf16* Kp = Kh + hb;
    const __bf16* Vp = Vt + hb;
    const int qrow0 = qb + wave * 16;

    bf16x8 qf[2];
#pragma unroll
    for (int kk = 0; kk < 2; ++kk)
        qf[kk] = *reinterpret_cast<const bf16x8*>(
            &Qp[(size_t)(qrow0 + l16) * DK_ + kk * 32 + g4 * 8]);

    f32x4 O[4];
#pragma unroll
    for (int n = 0; n < 4; ++n) O[n] = {0.f, 0.f, 0.f, 0.f};
    float m_run = -1e30f, l_run = 0.f;

    const int ntile = strip + 1;
    stage_swz<2>(Kp, DK_, Ks[0], t);
    stage_swz<2>(Vp, L_, Vs[0], t);
    __syncthreads();

    int cur = 0;
    for (int it = 0; it < ntile; ++it) {
        if (it + 1 < ntile) {
            stage_swz<2>(Kp + (size_t)(it + 1) * 64 * DK_, DK_, Ks[cur ^ 1], t);
            stage_swz<2>(Vp + (it + 1) * 64, L_, Vs[cur ^ 1], t);
        }
        const int kv0 = it * 64;

        f32x4 st[4];
#pragma unroll
        for (int n = 0; n < 4; ++n) st[n] = {0.f, 0.f, 0.f, 0.f};
        __builtin_amdgcn_s_setprio(1);
#pragma unroll
        for (int kk = 0; kk < 2; ++kk) {
            bf16x8 kf[4];
#pragma unroll
            for (int n = 0; n < 4; ++n)
                kf[n] = lds_frag(Ks[cur], n * 16 + l16, kk * 64 + g4 * 16);
#pragma unroll
            for (int n = 0; n < 4; ++n)
                st[n] = MFMA16(kf[n], qf[kk], st[n]);
        }
        __builtin_amdgcn_s_setprio(0);

        if (it == strip) {
            const int qg = qrow0 + l16;
#pragma unroll
            for (int n = 0; n < 4; ++n)
#pragma unroll
                for (int r = 0; r < 4; ++r)
                    if (kv0 + n * 16 + g4 * 4 + r > qg) st[n][r] = -1e30f;
        }

        float mx = st[0][0];
#pragma unroll
        for (int n = 0; n < 4; ++n)
#pragma unroll
            for (int r = 0; r < 4; ++r)
                if (n + r) mx = fmaxf(mx, st[n][r]);
        mx = fmaxf(mx, __shfl_xor(mx, 16));
        mx = fmaxf(mx, __shfl_xor(mx, 32));
        const float mxs = mx * SCALE2;

        const bool grow = !__all(mxs - m_run <= THR);
        float al = 1.f;
        if (grow) {
            const float mn = fmaxf(m_run, mxs);
            al = exp2f(m_run - mn);
            m_run = mn;
        }

        char* Pw = (char*)Ps + (wave * 16 + l16) * 128;
        float lb = 0.f;
#pragma unroll
        for (int n = 0; n < 4; ++n) {
            bf16x4 pv;
#pragma unroll
            for (int r = 0; r < 4; ++r) {
                const float p = exp2f(fmaf(st[n][r], SCALE2, -m_run));
                lb += p;
                pv[r] = (__bf16)p;
            }
            *(bf16x4*)(Pw + ((n * 32 + g4 * 8) ^ ((l16 & 7) << 4))) = pv;
        }
        lb += __shfl_xor(lb, 16);
        lb += __shfl_xor(lb, 32);
        l_run = al * l_run + lb;

        if (grow) {
#pragma unroll
            for (int r = 0; r < 4; ++r) {
                const float alr = __shfl(al, g4 * 4 + r);
#pragma unroll
                for (int n = 0; n < 4; ++n) O[n][r] *= alr;
            }
        }

        const __bf16* Pr = Ps + wave * 16 * 64;
        __builtin_amdgcn_s_setprio(1);
#pragma unroll
        for (int kk = 0; kk < 2; ++kk) {
            bf16x8 pa = lds_frag(Pr, l16, kk * 64 + g4 * 16);
            bf16x8 vf[4];
#pragma unroll
            for (int n = 0; n < 4; ++n)
                vf[n] = lds_frag(Vs[cur], n * 16 + l16, kk * 64 + g4 * 16);
#pragma unroll
            for (int n = 0; n < 4; ++n)
                O[n] = MFMA16(pa, vf[n], O[n]);
        }
        __builtin_amdgcn_s_setprio(0);

        __syncthreads();
        cur ^= 1;
    }

    const float rl = 1.0f / l_run;
#pragma unroll
    for (int r = 0; r < 4; ++r) {
        const float inv = __shfl(rl, g4 * 4 + r);
        const int qrow = qrow0 + g4 * 4 + r;
#pragma unroll
        for (int n = 0; n < 4; ++n)
            Xb[((size_t)b * L_ + qrow) * D_ + h * DK_ + n * 16 + l16] =
                (__bf16)(O[n][r] * inv);
    }
}

// ---------------------------------------------------------------------------
extern "C" void kernel_launch(void* const* d_in, const int* in_sizes, int n_in,
                              void* d_out, int out_size, void* d_ws, size_t ws_size,
                              hipStream_t stream)
{
    (void)in_sizes; (void)n_in; (void)out_size; (void)ws_size;
    const float* query = (const float*)d_in[0];
    const float* key   = (const float*)d_in[1];
    const float* value = (const float*)d_in[2];
    const float* Wq = (const float*)d_in[4];
    const float* bq = (const float*)d_in[5];
    const float* Wk = (const float*)d_in[6];
    const float* bk = (const float*)d_in[7];
    const float* Wv = (const float*)d_in[8];
    const float* bv = (const float*)d_in[9];
    const float* Wo = (const float*)d_in[10];
    const float* bo = (const float*)d_in[11];

    const size_t SZ = (size_t)B_ * L_ * D_;
    const size_t WSZ = (size_t)D_ * D_;
    __bf16* wsb = (__bf16*)d_ws;
    __bf16* qb_ = wsb;                            // q|k|v bf16 contiguous (ASEG)
    __bf16* Qh  = wsb + 3 * SZ;
    __bf16* Kh  = wsb + 4 * SZ;
    __bf16* Vt  = wsb + 5 * SZ;
    __bf16* Xb  = wsb + 6 * SZ;
    __bf16* Wqkv = wsb + 7 * SZ;                  // Wq|Wk|Wv [3072][1024]
    __bf16* Wob  = Wqkv + 3 * WSZ;

    CastArgs ca;
    ca.s[0] = query; ca.s[1] = key; ca.s[2] = value;
    ca.s[3] = Wq; ca.s[4] = Wk; ca.s[5] = Wv; ca.s[6] = Wo;
    ca.d[0] = qb_; ca.d[1] = qb_ + SZ; ca.d[2] = qb_ + 2 * SZ;
    ca.d[3] = Wqkv; ca.d[4] = Wqkv + WSZ; ca.d[5] = Wqkv + 2 * WSZ; ca.d[6] = Wob;
    ca.n[0] = ca.n[1] = ca.n[2] = (int)SZ;
    ca.n[3] = ca.n[4] = ca.n[5] = ca.n[6] = (int)WSZ;
    cast_all<<<dim3(1024, 7), 256, 0, stream>>>(ca);

    QKVDst qd;
    qd.bq = bq; qd.bk = bk; qd.bvv = bv;
    qd.qh = Qh; qd.kh = Kh; qd.vt = Vt;

    const int M = B_ * L_;
    gemm_bf16<3><<<64 * 48, 256, 0, stream>>>(qb_, Wqkv, nullptr, nullptr,
                                              M, 3 * D_, D_, qd);
    attn_mfma<<<32 * H_ * B_, 256, 0, stream>>>(Qh, Kh, Vt, Xb);
    gemm_bf16<2><<<64 * 16, 256, 0, stream>>>(Xb, Wob, bo, d_out, M, D_, D_, qd);
}